// Round 8
// baseline (236.518 us; speedup 1.0000x reference)
//
#include <hip/hip_runtime.h>
#include <cmath>

typedef __bf16 bf16;
typedef __bf16 bf16x8 __attribute__((ext_vector_type(8)));
typedef float f32x4 __attribute__((ext_vector_type(4)));

#define SBAR() __builtin_amdgcn_sched_barrier(0)

// B=16, C_IN=256, H=W=64, C_OUT=256, 3x3, stride 1, pad 1, CURV=1

__device__ inline void gload16(const void* g, void* l) {
    __builtin_amdgcn_global_load_lds(
        (const __attribute__((address_space(1))) unsigned int*)g,
        (__attribute__((address_space(3))) unsigned int*)l, 16, 0, 0);
}

// ---------------------------------------------------------------------------
// Weight transform: z[k=c*9+tap][co] -> zt4[s=cc*9+tap][gran8][co256][8ch] bf16
// (gran = 8-channel granule within the 64-ch chunk). Staging into LDS is a
// linear 32 KB copy per stage; the B frag read is consecutive-co (no swizzle).
__global__ void k_prep_zt(const float* __restrict__ z, bf16* __restrict__ zt4) {
    int s = blockIdx.x;                // 36 = cc*9 + tap
    int cc = s / 9, tap = s % 9;
    int co = threadIdx.x;
#pragma unroll
    for (int gran = 0; gran < 8; ++gran) {
        bf16x8 pk;
#pragma unroll
        for (int e = 0; e < 8; ++e) {
            int c = cc * 64 + gran * 8 + e;
            pk[e] = (bf16)z[(size_t)(c * 9 + tap) * 256 + co];
        }
        *(bf16x8*)(zt4 + ((size_t)(s * 8 + gran) * 256 + co) * 8) = pk;
    }
}

// Column constants
__global__ void k_prep_cols(const float* __restrict__ z, const float* __restrict__ r,
                            float* __restrict__ zn, float* __restrict__ ch,
                            float* __restrict__ sh) {
    __shared__ float red[256];
    int co = blockIdx.x, t = threadIdx.x;
    float s = 0.f;
    for (int i = 0; i < 9; ++i) {
        float v = z[(size_t)(i * 256 + t) * 256 + co];
        s += v * v;
    }
    red[t] = s;
    __syncthreads();
    for (int off = 128; off >= 1; off >>= 1) {
        if (t < off) red[t] += red[t + off];
        __syncthreads();
    }
    if (t == 0) {
        zn[co] = fmaxf(sqrtf(red[0]), 1e-15f);
        float tc = 2.f * r[co];
        ch[co] = coshf(tc);
        sh[co] = sinhf(tc);
    }
}

// ---------------------------------------------------------------------------
__global__ void k_logmap(const float* __restrict__ x, unsigned int* __restrict__ vt_u,
                         float* __restrict__ sq, float Rbeta) {
    __shared__ float tile[256][33];
    __shared__ float red[8][32];
    __shared__ float afac[32];
    int tid = threadIdx.x;
    int blk = blockIdx.x;
    int b = blk >> 7;
    int pix0 = (blk & 127) << 5;

    for (int it = 0; it < 32; ++it) {
        int c = it * 8 + (tid >> 5);
        int p = tid & 31;
        tile[c][p] = x[((size_t)b * 256 + c) * 4096 + pix0 + p];
    }
    __syncthreads();

    {
        int part = tid >> 5, p = tid & 31;
        float s = 0.f;
        for (int i = 0; i < 32; ++i) {
            float v = tile[part * 32 + i][p];
            s += v * v;
        }
        red[part][p] = s;
    }
    __syncthreads();
    if (tid < 32) {
        float n2 = 0.f;
        for (int i = 0; i < 8; ++i) n2 += red[i][tid];
        float n = sqrtf(n2);
        float nc = fmaxf(n, 1e-15f);
        float a = atanhf(fminf(nc, 0.9999999f)) / nc * Rbeta;
        afac[tid] = a;
        sq[(size_t)b * 4096 + pix0 + tid] = a * a * n2;
    }
    __syncthreads();

    for (int it = 0; it < 16; ++it) {
        int idx = it * 256 + tid;
        int p = idx >> 7;
        int cp = idx & 127;
        float a = afac[p];
        float v0 = a * tile[2 * cp][p];
        float v1 = a * tile[2 * cp + 1][p];
        union { bf16 h[2]; unsigned int u; } pk;
        pk.h[0] = (bf16)v0;
        pk.h[1] = (bf16)v1;
        vt_u[((size_t)b * 4096 + pix0 + p) * 128 + cp] = pk.u;
    }
}

__global__ void k_boxsum(const float* __restrict__ sq, float* __restrict__ nusq) {
    int idx = blockIdx.x * 256 + threadIdx.x;
    int b = idx >> 12, hw = idx & 4095, h = hw >> 6, w = hw & 63;
    const float* s = sq + ((size_t)b << 12);
    float acc = 0.f;
    for (int dh = -1; dh <= 1; ++dh) {
        int hh = h + dh;
        if ((unsigned)hh >= 64u) continue;
        for (int dw = -1; dw <= 1; ++dw) {
            int ww = w + dw;
            if ((unsigned)ww >= 64u) continue;
            acc += s[hh * 64 + ww];
        }
    }
    nusq[idx] = acc;
}

// ---------------------------------------------------------------------------
// Fused implicit-GEMM conv + hyperbolic FC epilogue, both operands LDS-staged.
// Same structure as round 7 (first-call-correct) with sched_barrier(0) fences
// pinning the stage-issue / waitcnt / s_barrier / compute program order (the
// round-7 replay race is attributed to compiler motion across the inline-asm
// barriers per guide rule #18).
//   A LDS: [r4][gran8][66 px] with zero-halo columns (pxslot 0,65) -> the
//     dw shift and clamp are ds_read immediate offsets; conflict-free.
//   B LDS: [gran8][co256], zt4 pre-transposed -> linear staging, immediate
//     offsets, conflict-free.
__launch_bounds__(1024)
__global__ void k_hconv(const bf16* __restrict__ vt, const bf16* __restrict__ zt4,
                        const float* __restrict__ nusq,
                        const float* __restrict__ znp, const float* __restrict__ chp,
                        const float* __restrict__ shp, float* __restrict__ out) {
    // A: 2 bufs x 32 (r,gran) units x 66 slots x 16B = 2 x 33792 B
    __shared__ __align__(1024) char Asb[2][33792];
    // B: 2 bufs x 8 gran x 256 co x 16B = 2 x 32768 B
    __shared__ __align__(1024) char Bsb[2][32768];
    __shared__ float s_lds[128], lam_lds[128];
    __shared__ float red[128][4];

    int tid = threadIdx.x;
    int bid = blockIdx.x;
    int bh = ((bid & 7) << 6) | (bid >> 3);   // XCD-bijective: 512 = 8 x 64
    int b = bh >> 5, h0 = (bh & 31) << 1;

    // zero the halo columns once (slots 0 and 65 of each (buf,r,gran) row)
    if (tid < 128) {
        int buf = tid >> 6, u = (tid >> 1) & 31, side = tid & 1;
        *(f32x4*)(Asb[buf] + u * 1056 + side * 65 * 16) = (f32x4){0.f, 0.f, 0.f, 0.f};
    }

    if (tid >= 128 && tid < 256) {
        int t = tid - 128;
        int h = h0 + (t >> 6), w = t & 63;
        float q = nusq[((size_t)b << 12) + h * 64 + w];
        float ncl = fmaxf(sqrtf(q), 1e-15f);
        float tt = tanhf(ncl);
        float s = tt / ncl;
        s_lds[t] = s;
        lam_lds[t] = 2.f / (1.f - s * s * q);
    }

    int wave = tid >> 6, lane = tid & 63;
    int wn = wave & 3, wm = wave >> 2;    // wm 0..3
    int lrow = lane & 15, lk = lane >> 4;
    int hloc = wm >> 1;                   // local image row 0/1
    int pxh = (wm & 1) << 5;              // px half base 0/32

    f32x4 acc[2][4];
#pragma unroll
    for (int m = 0; m < 2; ++m)
#pragma unroll
        for (int n = 0; n < 4; ++n) acc[m][n] = (f32x4){0.f, 0.f, 0.f, 0.f};

    const bf16* vb = vt + (((size_t)b) << 12) * 256;

    // stage A chunk cc: unit u = wave*2+it -> r = u>>3, gran = u&7;
    // dest = wave-uniform (u*1056 + 16); lane l lands at pxslot 1+l.
    auto stageA = [&](int buf, int cc) {
#pragma unroll
        for (int it = 0; it < 2; ++it) {
            int u = wave * 2 + it;
            int r = u >> 3, gran = u & 7;
            int hr = h0 - 1 + r;
            hr = hr < 0 ? 0 : (hr > 63 ? 63 : hr);   // garbage rows never read
            const bf16* g = vb + ((size_t)(hr * 64 + lane)) * 256 + cc * 64 + gran * 8;
            gload16(g, Asb[buf] + u * 1056 + 16);
        }
    };
    // stage B stage s: pure linear 32 KB copy
    auto stageB = [&](int buf, int s) {
        const char* src = (const char*)zt4 + (size_t)s * 32768;
#pragma unroll
        for (int it = 0; it < 2; ++it) {
            int u = wave * 2 + it;
            gload16(src + u * 1024 + lane * 16, Bsb[buf] + u * 1024);
        }
    };

    stageB(0, 0);
    stageA(0, 0);
    __syncthreads();                      // drains prologue; s_lds visible
    SBAR();

    // per-lane LDS read bases (the ONLY per-lane address math in the loop)
    const char* Ap0 = Asb[0] + (pxh + lrow) * 16 + lk * 1056;
    const char* Bp0 = Bsb[0] + wn * 1024 + lrow * 16 + lk * 4096;
    const int AbufStep = (int)(Asb[1] - Asb[0]);
    const int BbufStep = (int)(Bsb[1] - Bsb[0]);

#pragma unroll
    for (int cc = 0; cc < 4; ++cc) {
#pragma unroll
        for (int tap = 0; tap < 9; ++tap) {
            const int s = cc * 9 + tap;
            if (s < 35) stageB((s + 1) & 1, s + 1);
            if (tap == 0 && cc < 3) stageA((cc + 1) & 1, cc + 1);
            SBAR();                                   // pin issues before wait
            // FIFO-derived counted waits (B issued before A at tap==0):
            if (s == 35) {
                asm volatile("s_waitcnt vmcnt(0)" ::: "memory");
            } else if (cc < 3 && tap < 2) {
                asm volatile("s_waitcnt vmcnt(4)" ::: "memory");
            } else {
                asm volatile("s_waitcnt vmcnt(2)" ::: "memory");
            }
            SBAR();
            asm volatile("s_barrier" ::: "memory");   // stage-s data ready
            SBAR();

            const int dh = tap / 3 - 1, dw = tap % 3 - 1;
            int hh = h0 + hloc + dh;
            if ((unsigned)hh < 64u) {                 // wave-uniform
                const char* Ap = Ap0 + (cc & 1) * AbufStep;
                const char* Bp = Bp0 + (s & 1) * BbufStep;
                const int r = hloc + dh + 1;
                const int aoff = r * 8448 + (dw + 1) * 16;
#pragma unroll
                for (int ks = 0; ks < 2; ++ks) {
                    bf16x8 a0 = *(const bf16x8*)(Ap + (aoff + ks * 4224));
                    bf16x8 a1 = *(const bf16x8*)(Ap + (aoff + ks * 4224 + 256));
                    bf16x8 b0 = *(const bf16x8*)(Bp + (ks * 16384));
                    bf16x8 b1 = *(const bf16x8*)(Bp + (ks * 16384 + 256));
                    bf16x8 b2 = *(const bf16x8*)(Bp + (ks * 16384 + 512));
                    bf16x8 b3 = *(const bf16x8*)(Bp + (ks * 16384 + 768));
                    __builtin_amdgcn_s_setprio(1);
                    acc[0][0] = __builtin_amdgcn_mfma_f32_16x16x32_bf16(a0, b0, acc[0][0], 0, 0, 0);
                    acc[1][0] = __builtin_amdgcn_mfma_f32_16x16x32_bf16(a1, b0, acc[1][0], 0, 0, 0);
                    acc[0][1] = __builtin_amdgcn_mfma_f32_16x16x32_bf16(a0, b1, acc[0][1], 0, 0, 0);
                    acc[1][1] = __builtin_amdgcn_mfma_f32_16x16x32_bf16(a1, b1, acc[1][1], 0, 0, 0);
                    acc[0][2] = __builtin_amdgcn_mfma_f32_16x16x32_bf16(a0, b2, acc[0][2], 0, 0, 0);
                    acc[1][2] = __builtin_amdgcn_mfma_f32_16x16x32_bf16(a1, b2, acc[1][2], 0, 0, 0);
                    acc[0][3] = __builtin_amdgcn_mfma_f32_16x16x32_bf16(a0, b3, acc[0][3], 0, 0, 0);
                    acc[1][3] = __builtin_amdgcn_mfma_f32_16x16x32_bf16(a1, b3, acc[1][3], 0, 0, 0);
                    __builtin_amdgcn_s_setprio(0);
                }
            }
            SBAR();                                   // pin compute before release
            asm volatile("s_barrier" ::: "memory");   // reads done pre-restage
            SBAR();
        }
    }

    // ---------------- epilogue ----------------
    float znv[4], chv[4], shv[4];
#pragma unroll
    for (int n = 0; n < 4; ++n) {
        int co = wn * 64 + n * 16 + lrow;
        znv[n] = znp[co];
        chv[n] = chp[co];
        shv[n] = shp[co];
    }

#pragma unroll
    for (int m = 0; m < 2; ++m) {
#pragma unroll
        for (int r = 0; r < 4; ++r) {
            int wp = wm * 32 + m * 16 + 4 * lk + r;   // block-local px slot
            float s = s_lds[wp], lam = lam_lds[wp];
            float psum = 0.f;
#pragma unroll
            for (int n = 0; n < 4; ++n) {
                float xz = s * acc[m][n][r];
                float inner = lam * xz / znv[n] * chv[n] - (lam - 1.f) * shv[n];
                float vhp = 2.f * znv[n] * asinhf(inner);
                float w = sinhf(vhp);
                acc[m][n][r] = w;
                psum += w * w;
            }
            psum += __shfl_xor(psum, 1);
            psum += __shfl_xor(psum, 2);
            psum += __shfl_xor(psum, 4);
            psum += __shfl_xor(psum, 8);
            if (lrow == 0) red[wp][wn] = psum;
        }
    }
    __syncthreads();

    float* ob = out + (size_t)b * 256 * 4096 + (h0 + hloc) * 64 + pxh;
#pragma unroll
    for (int m = 0; m < 2; ++m) {
#pragma unroll
        for (int n = 0; n < 4; ++n) {
            int co = wn * 64 + n * 16 + lrow;
            f32x4 o;
#pragma unroll
            for (int r = 0; r < 4; ++r) {
                int wp = wm * 32 + m * 16 + 4 * lk + r;
                float tot = red[wp][0] + red[wp][1] + red[wp][2] + red[wp][3];
                o[r] = acc[m][n][r] / (1.f + sqrtf(1.f + tot));
            }
            *(f32x4*)(ob + (size_t)co * 4096 + m * 16 + 4 * lk) = o;
        }
    }
}

// ---------------------------------------------------------------------------
extern "C" void kernel_launch(void* const* d_in, const int* in_sizes, int n_in,
                              void* d_out, int out_size, void* d_ws, size_t ws_size,
                              hipStream_t stream) {
    const float* x = (const float*)d_in[0];   // [16,256,64,64]
    const float* z = (const float*)d_in[1];   // [2304,256]
    const float* r = (const float*)d_in[2];   // [256]
    float* out = (float*)d_out;               // [16,256,64,64]

    char* ws = (char*)d_ws;
    bf16* vt = (bf16*)ws;                         // 33,554,432 B
    float* sq = (float*)(ws + 33554432);
    float* nusq = (float*)(ws + 33816576);
    bf16* zt4 = (bf16*)(ws + 34078720);           // 36*32KB = 1,179,648 B
    float* zn = (float*)(ws + 35258368);
    float* ch = (float*)(ws + 35259392);
    float* sh = (float*)(ws + 35260416);
    if (ws_size < 35261440) return;

    double bni = lgamma(128.0) + lgamma(0.5) - lgamma(128.5);
    double bn = lgamma(1152.0) + lgamma(0.5) - lgamma(1152.5);
    float Rbeta = (float)exp(bn - bni);

    k_prep_zt<<<36, 256, 0, stream>>>(z, zt4);
    k_prep_cols<<<256, 256, 0, stream>>>(z, r, zn, ch, sh);
    k_logmap<<<2048, 256, 0, stream>>>(x, (unsigned int*)vt, sq, Rbeta);
    k_boxsum<<<256, 256, 0, stream>>>(sq, nusq);
    k_hconv<<<512, 1024, 0, stream>>>(vt, zt4, nusq, zn, ch, sh, out);
}

// Round 9
// 147.876 us; speedup vs baseline: 1.5994x; 1.5994x over previous
//
#include <hip/hip_runtime.h>
#include <cmath>

typedef __bf16 bf16;
typedef __bf16 bf16x8 __attribute__((ext_vector_type(8)));
typedef float f32x4 __attribute__((ext_vector_type(4)));

#define SBAR() __builtin_amdgcn_sched_barrier(0)

// B=16, C_IN=256, H=W=64, C_OUT=256, 3x3, stride 1, pad 1, CURV=1

__device__ inline void gload16(const void* g, void* l) {
    __builtin_amdgcn_global_load_lds(
        (const __attribute__((address_space(1))) unsigned int*)g,
        (__attribute__((address_space(3))) unsigned int*)l, 16, 0, 0);
}

// ---------------------------------------------------------------------------
// Weight transform: z[k=c*9+tap][co] -> zt5[s=cc*9+tap][gran4][co256][8ch] bf16
// s-chunk = 32 channels (4 granules). LDS staging is a linear 16 KB copy.
__global__ void k_prep_zt(const float* __restrict__ z, bf16* __restrict__ zt5) {
    int s = blockIdx.x;                // 72 = cc*9 + tap, cc in 0..7 (32ch)
    int cc = s / 9, tap = s % 9;
    int co = threadIdx.x;
#pragma unroll
    for (int g = 0; g < 4; ++g) {
        bf16x8 pk;
#pragma unroll
        for (int e = 0; e < 8; ++e) {
            int c = cc * 32 + g * 8 + e;
            pk[e] = (bf16)z[(size_t)(c * 9 + tap) * 256 + co];
        }
        *(bf16x8*)(zt5 + ((size_t)(s * 4 + g) * 256 + co) * 8) = pk;
    }
}

// Column constants
__global__ void k_prep_cols(const float* __restrict__ z, const float* __restrict__ r,
                            float* __restrict__ zn, float* __restrict__ ch,
                            float* __restrict__ sh) {
    __shared__ float red[256];
    int co = blockIdx.x, t = threadIdx.x;
    float s = 0.f;
    for (int i = 0; i < 9; ++i) {
        float v = z[(size_t)(i * 256 + t) * 256 + co];
        s += v * v;
    }
    red[t] = s;
    __syncthreads();
    for (int off = 128; off >= 1; off >>= 1) {
        if (t < off) red[t] += red[t + off];
        __syncthreads();
    }
    if (t == 0) {
        zn[co] = fmaxf(sqrtf(red[0]), 1e-15f);
        float tc = 2.f * r[co];
        ch[co] = coshf(tc);
        sh[co] = sinhf(tc);
    }
}

// ---------------------------------------------------------------------------
__global__ void k_logmap(const float* __restrict__ x, unsigned int* __restrict__ vt_u,
                         float* __restrict__ sq, float Rbeta) {
    __shared__ float tile[256][33];
    __shared__ float red[8][32];
    __shared__ float afac[32];
    int tid = threadIdx.x;
    int blk = blockIdx.x;
    int b = blk >> 7;
    int pix0 = (blk & 127) << 5;

    for (int it = 0; it < 32; ++it) {
        int c = it * 8 + (tid >> 5);
        int p = tid & 31;
        tile[c][p] = x[((size_t)b * 256 + c) * 4096 + pix0 + p];
    }
    __syncthreads();

    {
        int part = tid >> 5, p = tid & 31;
        float s = 0.f;
        for (int i = 0; i < 32; ++i) {
            float v = tile[part * 32 + i][p];
            s += v * v;
        }
        red[part][p] = s;
    }
    __syncthreads();
    if (tid < 32) {
        float n2 = 0.f;
        for (int i = 0; i < 8; ++i) n2 += red[i][tid];
        float n = sqrtf(n2);
        float nc = fmaxf(n, 1e-15f);
        float a = atanhf(fminf(nc, 0.9999999f)) / nc * Rbeta;
        afac[tid] = a;
        sq[(size_t)b * 4096 + pix0 + tid] = a * a * n2;
    }
    __syncthreads();

    for (int it = 0; it < 16; ++it) {
        int idx = it * 256 + tid;
        int p = idx >> 7;
        int cp = idx & 127;
        float a = afac[p];
        float v0 = a * tile[2 * cp][p];
        float v1 = a * tile[2 * cp + 1][p];
        union { bf16 h[2]; unsigned int u; } pk;
        pk.h[0] = (bf16)v0;
        pk.h[1] = (bf16)v1;
        vt_u[((size_t)b * 4096 + pix0 + p) * 128 + cp] = pk.u;
    }
}

__global__ void k_boxsum(const float* __restrict__ sq, float* __restrict__ nusq) {
    int idx = blockIdx.x * 256 + threadIdx.x;
    int b = idx >> 12, hw = idx & 4095, h = hw >> 6, w = hw & 63;
    const float* s = sq + ((size_t)b << 12);
    float acc = 0.f;
    for (int dh = -1; dh <= 1; ++dh) {
        int hh = h + dh;
        if ((unsigned)hh >= 64u) continue;
        for (int dw = -1; dw <= 1; ++dw) {
            int ww = w + dw;
            if ((unsigned)ww >= 64u) continue;
            acc += s[hh * 64 + ww];
        }
    }
    nusq[idx] = acc;
}

// ---------------------------------------------------------------------------
// Fused implicit-GEMM conv + hyperbolic FC epilogue.
// Round-8 diagnosis: LDS-read-BW-bound at 0.75 ds_read/MFMA (ceiling ~18%
// MfmaUtil, measured 14%). This version halves reads/MFMA to 0.375:
//   Block: 4 image rows (256 px) x 256 co, 8 waves (512 thr).
//   Wave: 64 px x 128 co -> acc[4][8] = 128 VGPRs (waves_per_eu(2,2) ->
//   256-reg budget; NO launch_bounds cap -- rounds 2-4 spilled under caps).
//   K: 72 stages = cc(8 x 32ch) x tap(9).
//   A LDS [6r][4g][66px-halo]x16B (25 KB, dbuf), B LDS [4g pad16][256co]
//   (16 KB, dbuf). Counted vmcnt (B=2 loads, A=3 loads), raw barriers, SBAR
//   fences (round-7/8 race lesson).
__global__ void
__attribute__((amdgpu_flat_work_group_size(512, 512)))
__attribute__((amdgpu_waves_per_eu(2, 2)))
k_hconv(const bf16* __restrict__ vt, const bf16* __restrict__ zt5,
        const float* __restrict__ nusq,
        const float* __restrict__ znp, const float* __restrict__ chp,
        const float* __restrict__ shp, float* __restrict__ out) {
    __shared__ __align__(1024) char Asb[2][25344];   // 24 units x 1056B
    __shared__ __align__(1024) char Bsb[2][16448];   // 4 gran x (4096+16)B
    __shared__ float s_lds[256], lam_lds[256];
    __shared__ float red[256][2];

    int tid = threadIdx.x;
    int bid = blockIdx.x;
    int bh = ((bid & 7) << 5) | (bid >> 3);   // XCD-bijective: 256 = 8 x 32
    int b = bh >> 4, h0 = (bh & 15) << 2;

    // zero the halo slots (0 and 65) of each (buf, unit) row, once
    if (tid < 96) {
        int buf = tid / 48, rem = tid % 48;
        int u = rem >> 1, side = rem & 1;
        *(f32x4*)(Asb[buf] + u * 1056 + side * 1040) = (f32x4){0.f, 0.f, 0.f, 0.f};
    }

    if (tid >= 256) {
        int t = tid - 256;
        int h = h0 + (t >> 6), w = t & 63;
        float q = nusq[((size_t)b << 12) + h * 64 + w];
        float ncl = fmaxf(sqrtf(q), 1e-15f);
        float p = __expf(2.f * ncl);
        float tt = (p - 1.f) / (p + 1.f);        // tanh(ncl)
        s_lds[t] = tt / ncl;                     // expmap scale
        lam_lds[t] = 2.f / (1.f - tt * tt);
    }

    int wave = tid >> 6, lane = tid & 63;
    int wn = wave & 1, wm = wave >> 1;    // wm row 0..3, wn co-half 0..1
    int lrow = lane & 15, lk = lane >> 4;

    f32x4 acc[4][8];
#pragma unroll
    for (int m = 0; m < 4; ++m)
#pragma unroll
        for (int n = 0; n < 8; ++n) acc[m][n] = (f32x4){0.f, 0.f, 0.f, 0.f};

    const bf16* vb = vt + (((size_t)b) << 12) * 256;

    // stage A chunk cc: 24 units (r6 x g4) of one 66-slot px row; 3/wave
    auto stageA = [&](int buf, int cc) {
#pragma unroll
        for (int it = 0; it < 3; ++it) {
            int u = wave * 3 + it;
            int r = u >> 2, g = u & 3;
            int hr = h0 - 1 + r;
            hr = hr < 0 ? 0 : (hr > 63 ? 63 : hr);   // clamped rows never read
            const bf16* gp = vb + ((size_t)(hr * 64 + lane)) * 256 + cc * 32 + g * 8;
            gload16(gp, Asb[buf] + u * 1056 + 16);
        }
    };
    // stage B stage s: 16 units of 1 KB, pad-16B per granule; 2/wave
    auto stageB = [&](int buf, int s) {
        const char* src = (const char*)zt5 + (size_t)s * 16384;
#pragma unroll
        for (int it = 0; it < 2; ++it) {
            int u = wave * 2 + it;
            gload16(src + u * 1024 + lane * 16,
                    Bsb[buf] + (u >> 2) * 4112 + (u & 3) * 1024);
        }
    };

    stageB(0, 0);
    stageA(0, 0);
    __syncthreads();                      // drains prologue; s_lds visible
    SBAR();

    // per-lane LDS read bases
    const char* Ap0 = Asb[0] + lk * 1056 + (lrow + 1) * 16;
    const char* Bp0 = Bsb[0] + lk * 4112 + (wn * 128 + lrow) * 16;

#pragma unroll
    for (int cc = 0; cc < 8; ++cc) {
#pragma unroll
        for (int tap = 0; tap < 9; ++tap) {
            const int s = cc * 9 + tap;
            if (s < 71) stageB((s + 1) & 1, s + 1);
            if (tap == 0 && cc < 7) stageA((cc + 1) & 1, cc + 1);
            SBAR();
            // FIFO-derived counted waits (B=2 loads, A=3 loads):
            if (s == 71) {
                asm volatile("s_waitcnt vmcnt(0)" ::: "memory");
            } else if (cc < 7 && tap < 2) {
                asm volatile("s_waitcnt vmcnt(5)" ::: "memory");
            } else {
                asm volatile("s_waitcnt vmcnt(2)" ::: "memory");
            }
            SBAR();
            asm volatile("s_barrier" ::: "memory");   // stage-s data ready
            SBAR();

            const int dh = tap / 3 - 1, dw = tap % 3 - 1;
            int hh = h0 + wm + dh;
            if ((unsigned)hh < 64u) {                 // wave-uniform skip
                const char* Ap = Ap0 + (cc & 1) * 25344 + (wm + dh + 1) * 4224;
                const char* Bp = Bp0 + (s & 1) * 16448;
                bf16x8 a0 = *(const bf16x8*)(Ap + (0 * 16 + dw * 16));
                bf16x8 a1 = *(const bf16x8*)(Ap + (16 * 16 + dw * 16));
                bf16x8 a2 = *(const bf16x8*)(Ap + (32 * 16 + dw * 16));
                bf16x8 a3 = *(const bf16x8*)(Ap + (48 * 16 + dw * 16));
#pragma unroll
                for (int nh = 0; nh < 2; ++nh) {      // n in halves of 4
                    bf16x8 b0 = *(const bf16x8*)(Bp + (nh * 1024));
                    bf16x8 b1 = *(const bf16x8*)(Bp + (nh * 1024 + 256));
                    bf16x8 b2 = *(const bf16x8*)(Bp + (nh * 1024 + 512));
                    bf16x8 b3 = *(const bf16x8*)(Bp + (nh * 1024 + 768));
                    __builtin_amdgcn_s_setprio(1);
                    acc[0][nh*4+0] = __builtin_amdgcn_mfma_f32_16x16x32_bf16(a0, b0, acc[0][nh*4+0], 0, 0, 0);
                    acc[1][nh*4+0] = __builtin_amdgcn_mfma_f32_16x16x32_bf16(a1, b0, acc[1][nh*4+0], 0, 0, 0);
                    acc[2][nh*4+0] = __builtin_amdgcn_mfma_f32_16x16x32_bf16(a2, b0, acc[2][nh*4+0], 0, 0, 0);
                    acc[3][nh*4+0] = __builtin_amdgcn_mfma_f32_16x16x32_bf16(a3, b0, acc[3][nh*4+0], 0, 0, 0);
                    acc[0][nh*4+1] = __builtin_amdgcn_mfma_f32_16x16x32_bf16(a0, b1, acc[0][nh*4+1], 0, 0, 0);
                    acc[1][nh*4+1] = __builtin_amdgcn_mfma_f32_16x16x32_bf16(a1, b1, acc[1][nh*4+1], 0, 0, 0);
                    acc[2][nh*4+1] = __builtin_amdgcn_mfma_f32_16x16x32_bf16(a2, b1, acc[2][nh*4+1], 0, 0, 0);
                    acc[3][nh*4+1] = __builtin_amdgcn_mfma_f32_16x16x32_bf16(a3, b1, acc[3][nh*4+1], 0, 0, 0);
                    acc[0][nh*4+2] = __builtin_amdgcn_mfma_f32_16x16x32_bf16(a0, b2, acc[0][nh*4+2], 0, 0, 0);
                    acc[1][nh*4+2] = __builtin_amdgcn_mfma_f32_16x16x32_bf16(a1, b2, acc[1][nh*4+2], 0, 0, 0);
                    acc[2][nh*4+2] = __builtin_amdgcn_mfma_f32_16x16x32_bf16(a2, b2, acc[2][nh*4+2], 0, 0, 0);
                    acc[3][nh*4+2] = __builtin_amdgcn_mfma_f32_16x16x32_bf16(a3, b2, acc[3][nh*4+2], 0, 0, 0);
                    acc[0][nh*4+3] = __builtin_amdgcn_mfma_f32_16x16x32_bf16(a0, b3, acc[0][nh*4+3], 0, 0, 0);
                    acc[1][nh*4+3] = __builtin_amdgcn_mfma_f32_16x16x32_bf16(a1, b3, acc[1][nh*4+3], 0, 0, 0);
                    acc[2][nh*4+3] = __builtin_amdgcn_mfma_f32_16x16x32_bf16(a2, b3, acc[2][nh*4+3], 0, 0, 0);
                    acc[3][nh*4+3] = __builtin_amdgcn_mfma_f32_16x16x32_bf16(a3, b3, acc[3][nh*4+3], 0, 0, 0);
                    __builtin_amdgcn_s_setprio(0);
                }
            }
            SBAR();
            asm volatile("s_barrier" ::: "memory");   // reads done pre-restage
            SBAR();
        }
    }

    // ---------------- epilogue (fast transcendental forms) ----------------
    float cz[8], sh8[8], tz[8];
#pragma unroll
    for (int n = 0; n < 8; ++n) {
        int co = wn * 128 + n * 16 + lrow;
        float zn = znp[co];
        cz[n] = chp[co] / zn;
        sh8[n] = shp[co];
        tz[n] = 2.f * zn;
    }

#pragma unroll
    for (int m = 0; m < 4; ++m) {
#pragma unroll
        for (int r = 0; r < 4; ++r) {
            int wp = wm * 64 + m * 16 + 4 * lk + r;   // block-local px slot
            float s = s_lds[wp], lam = lam_lds[wp];
            float lm1 = lam - 1.f;
            float psum = 0.f;
#pragma unroll
            for (int n = 0; n < 8; ++n) {
                float xz = s * acc[m][n][r];
                float inner = lam * xz * cz[n] - lm1 * sh8[n];
                float as = __logf(inner + sqrtf(inner * inner + 1.f)); // asinh
                float p = __expf(tz[n] * as);
                float w = 0.5f * (p - __builtin_amdgcn_rcpf(p));       // sinh
                acc[m][n][r] = w;
                psum += w * w;
            }
            psum += __shfl_xor(psum, 1);
            psum += __shfl_xor(psum, 2);
            psum += __shfl_xor(psum, 4);
            psum += __shfl_xor(psum, 8);
            if (lrow == 0) red[wp][wn] = psum;
        }
    }
    __syncthreads();

    float dinv[4][4];
#pragma unroll
    for (int m = 0; m < 4; ++m)
#pragma unroll
        for (int r = 0; r < 4; ++r) {
            int wp = wm * 64 + m * 16 + 4 * lk + r;
            float tot = red[wp][0] + red[wp][1];
            dinv[m][r] = __builtin_amdgcn_rcpf(1.f + sqrtf(1.f + tot));
        }

    float* ob = out + (size_t)b * 256 * 4096 + (h0 + wm) * 64;
#pragma unroll
    for (int m = 0; m < 4; ++m) {
#pragma unroll
        for (int n = 0; n < 8; ++n) {
            int co = wn * 128 + n * 16 + lrow;
            f32x4 o;
#pragma unroll
            for (int r = 0; r < 4; ++r) o[r] = acc[m][n][r] * dinv[m][r];
            *(f32x4*)(ob + (size_t)co * 4096 + m * 16 + 4 * lk) = o;
        }
    }
}

// ---------------------------------------------------------------------------
extern "C" void kernel_launch(void* const* d_in, const int* in_sizes, int n_in,
                              void* d_out, int out_size, void* d_ws, size_t ws_size,
                              hipStream_t stream) {
    const float* x = (const float*)d_in[0];   // [16,256,64,64]
    const float* z = (const float*)d_in[1];   // [2304,256]
    const float* r = (const float*)d_in[2];   // [256]
    float* out = (float*)d_out;               // [16,256,64,64]

    char* ws = (char*)d_ws;
    bf16* vt = (bf16*)ws;                         // 33,554,432 B
    float* sq = (float*)(ws + 33554432);
    float* nusq = (float*)(ws + 33816576);
    bf16* zt5 = (bf16*)(ws + 34078720);           // 72*16KB = 1,179,648 B
    float* zn = (float*)(ws + 35258368);
    float* ch = (float*)(ws + 35259392);
    float* sh = (float*)(ws + 35260416);
    if (ws_size < 35261440) return;

    double bni = lgamma(128.0) + lgamma(0.5) - lgamma(128.5);
    double bn = lgamma(1152.0) + lgamma(0.5) - lgamma(1152.5);
    float Rbeta = (float)exp(bn - bni);

    k_prep_zt<<<72, 256, 0, stream>>>(z, zt5);
    k_prep_cols<<<256, 256, 0, stream>>>(z, r, zn, ch, sh);
    k_logmap<<<2048, 256, 0, stream>>>(x, (unsigned int*)vt, sq, Rbeta);
    k_boxsum<<<256, 256, 0, stream>>>(sq, nusq);
    k_hconv<<<256, 512, 0, stream>>>(vt, zt5, nusq, zn, ch, sh, out);
}

// Round 10
// 144.547 us; speedup vs baseline: 1.6363x; 1.0230x over previous
//
#include <hip/hip_runtime.h>
#include <cmath>

typedef __bf16 bf16;
typedef __bf16 bf16x8 __attribute__((ext_vector_type(8)));
typedef float f32x4 __attribute__((ext_vector_type(4)));

#define SBAR() __builtin_amdgcn_sched_barrier(0)

// B=16, C_IN=256, H=W=64, C_OUT=256, 3x3, stride 1, pad 1, CURV=1

__device__ inline void gload16(const void* g, void* l) {
    __builtin_amdgcn_global_load_lds(
        (const __attribute__((address_space(1))) unsigned int*)g,
        (__attribute__((address_space(3))) unsigned int*)l, 16, 0, 0);
}

// ---------------------------------------------------------------------------
// Weight transform: z[k=c*9+tap][co] -> zt5[s=cc*9+tap][gran4][co256][8ch] bf16
__global__ void k_prep_zt(const float* __restrict__ z, bf16* __restrict__ zt5) {
    int s = blockIdx.x;                // 72 = cc*9 + tap, cc in 0..7 (32ch)
    int cc = s / 9, tap = s % 9;
    int co = threadIdx.x;
#pragma unroll
    for (int g = 0; g < 4; ++g) {
        bf16x8 pk;
#pragma unroll
        for (int e = 0; e < 8; ++e) {
            int c = cc * 32 + g * 8 + e;
            pk[e] = (bf16)z[(size_t)(c * 9 + tap) * 256 + co];
        }
        *(bf16x8*)(zt5 + ((size_t)(s * 4 + g) * 256 + co) * 8) = pk;
    }
}

// Column constants
__global__ void k_prep_cols(const float* __restrict__ z, const float* __restrict__ r,
                            float* __restrict__ zn, float* __restrict__ ch,
                            float* __restrict__ sh) {
    __shared__ float red[256];
    int co = blockIdx.x, t = threadIdx.x;
    float s = 0.f;
    for (int i = 0; i < 9; ++i) {
        float v = z[(size_t)(i * 256 + t) * 256 + co];
        s += v * v;
    }
    red[t] = s;
    __syncthreads();
    for (int off = 128; off >= 1; off >>= 1) {
        if (t < off) red[t] += red[t + off];
        __syncthreads();
    }
    if (t == 0) {
        zn[co] = fmaxf(sqrtf(red[0]), 1e-15f);
        float tc = 2.f * r[co];
        ch[co] = coshf(tc);
        sh[co] = sinhf(tc);
    }
}

// ---------------------------------------------------------------------------
__global__ void k_logmap(const float* __restrict__ x, unsigned int* __restrict__ vt_u,
                         float* __restrict__ sq, float Rbeta) {
    __shared__ float tile[256][33];
    __shared__ float red[8][32];
    __shared__ float afac[32];
    int tid = threadIdx.x;
    int blk = blockIdx.x;
    int b = blk >> 7;
    int pix0 = (blk & 127) << 5;

    for (int it = 0; it < 32; ++it) {
        int c = it * 8 + (tid >> 5);
        int p = tid & 31;
        tile[c][p] = x[((size_t)b * 256 + c) * 4096 + pix0 + p];
    }
    __syncthreads();

    {
        int part = tid >> 5, p = tid & 31;
        float s = 0.f;
        for (int i = 0; i < 32; ++i) {
            float v = tile[part * 32 + i][p];
            s += v * v;
        }
        red[part][p] = s;
    }
    __syncthreads();
    if (tid < 32) {
        float n2 = 0.f;
        for (int i = 0; i < 8; ++i) n2 += red[i][tid];
        float n = sqrtf(n2);
        float nc = fmaxf(n, 1e-15f);
        float a = atanhf(fminf(nc, 0.9999999f)) / nc * Rbeta;
        afac[tid] = a;
        sq[(size_t)b * 4096 + pix0 + tid] = a * a * n2;
    }
    __syncthreads();

    for (int it = 0; it < 16; ++it) {
        int idx = it * 256 + tid;
        int p = idx >> 7;
        int cp = idx & 127;
        float a = afac[p];
        float v0 = a * tile[2 * cp][p];
        float v1 = a * tile[2 * cp + 1][p];
        union { bf16 h[2]; unsigned int u; } pk;
        pk.h[0] = (bf16)v0;
        pk.h[1] = (bf16)v1;
        vt_u[((size_t)b * 4096 + pix0 + p) * 128 + cp] = pk.u;
    }
}

__global__ void k_boxsum(const float* __restrict__ sq, float* __restrict__ nusq) {
    int idx = blockIdx.x * 256 + threadIdx.x;
    int b = idx >> 12, hw = idx & 4095, h = hw >> 6, w = hw & 63;
    const float* s = sq + ((size_t)b << 12);
    float acc = 0.f;
    for (int dh = -1; dh <= 1; ++dh) {
        int hh = h + dh;
        if ((unsigned)hh >= 64u) continue;
        for (int dw = -1; dw <= 1; ++dw) {
            int ww = w + dw;
            if ((unsigned)ww >= 64u) continue;
            acc += s[hh * 64 + ww];
        }
    }
    nusq[idx] = acc;
}

// ---------------------------------------------------------------------------
// Fused implicit-GEMM conv + hyperbolic FC epilogue.
// Round-9 lesson: the fully-unrolled 72-stage body (~35 KB) overflows the
// 32 KB L1I -> front-end bound (nothing else saturated). This version ROLLS
// the cc loop (#pragma unroll 1) and unrolls only the 9 taps (~4 KB body).
// Same layouts/waits as round 9:
//   Block: 4 image rows x 256 co, 8 waves. Wave: 64 px x 128 co (acc[4][8]).
//   A LDS [6r][4g][66px-halo] 25 KB dbuf; B LDS [4g pad16][256co] 16 KB dbuf.
//   Counted vmcnt (B=2 loads, A=3), raw barriers, SBAR fences (r7/8 lesson).
__global__ void
__attribute__((amdgpu_flat_work_group_size(512, 512)))
__attribute__((amdgpu_waves_per_eu(2, 2)))
k_hconv(const bf16* __restrict__ vt, const bf16* __restrict__ zt5,
        const float* __restrict__ nusq,
        const float* __restrict__ znp, const float* __restrict__ chp,
        const float* __restrict__ shp, float* __restrict__ out) {
    __shared__ __align__(1024) char Asb[2][25344];   // 24 units x 1056B
    __shared__ __align__(1024) char Bsb[2][16448];   // 4 gran x (4096+16)B
    __shared__ float s_lds[256], lam_lds[256];
    __shared__ float red[256][2];

    int tid = threadIdx.x;
    int bid = blockIdx.x;
    int bh = ((bid & 7) << 5) | (bid >> 3);   // XCD-bijective: 256 = 8 x 32
    int b = bh >> 4, h0 = (bh & 15) << 2;

    // zero the halo slots (0 and 65) of each (buf, unit) row, once
    if (tid < 96) {
        int buf = tid / 48, rem = tid % 48;
        int u = rem >> 1, side = rem & 1;
        *(f32x4*)(Asb[buf] + u * 1056 + side * 1040) = (f32x4){0.f, 0.f, 0.f, 0.f};
    }

    if (tid >= 256) {
        int t = tid - 256;
        int h = h0 + (t >> 6), w = t & 63;
        float q = nusq[((size_t)b << 12) + h * 64 + w];
        float ncl = fmaxf(sqrtf(q), 1e-15f);
        float p = __expf(2.f * ncl);
        float tt = (p - 1.f) / (p + 1.f);        // tanh(ncl)
        s_lds[t] = tt / ncl;                     // expmap scale
        lam_lds[t] = 2.f / (1.f - tt * tt);
    }

    int wave = tid >> 6, lane = tid & 63;
    int wn = wave & 1, wm = wave >> 1;    // wm row 0..3, wn co-half 0..1
    int lrow = lane & 15, lk = lane >> 4;

    f32x4 acc[4][8];
#pragma unroll
    for (int m = 0; m < 4; ++m)
#pragma unroll
        for (int n = 0; n < 8; ++n) acc[m][n] = (f32x4){0.f, 0.f, 0.f, 0.f};

    const bf16* vb = vt + (((size_t)b) << 12) * 256;

    // stage A chunk ccn into dst buffer: 24 units (r6 x g4); 3 loads/wave
    auto stageA = [&](char* dst, int ccn) {
#pragma unroll
        for (int it = 0; it < 3; ++it) {
            int u = wave * 3 + it;
            int r = u >> 2, g = u & 3;
            int hr = h0 - 1 + r;
            hr = hr < 0 ? 0 : (hr > 63 ? 63 : hr);   // clamped rows never read
            const bf16* gp = vb + ((size_t)(hr * 64 + lane)) * 256 + ccn * 32 + g * 8;
            gload16(gp, dst + u * 1056 + 16);
        }
    };
    // stage B stage snext into dst: linear 16 KB copy; 2 loads/wave
    auto stageB = [&](char* dst, int snext) {
        const char* src = (const char*)zt5 + (size_t)snext * 16384;
#pragma unroll
        for (int it = 0; it < 2; ++it) {
            int u = wave * 2 + it;
            gload16(src + u * 1024 + lane * 16,
                    dst + (u >> 2) * 4112 + (u & 3) * 1024);
        }
    };

    stageB((char*)Bsb[0], 0);
    stageA((char*)Asb[0], 0);
    __syncthreads();                      // drains prologue; s_lds visible
    SBAR();

    // per-lane invariant offsets
    const int aBase = lk * 1056 + lrow * 16;              // + wm row below
    const int bBase = lk * 4112 + (wn * 128 + lrow) * 16;

#pragma unroll 1
    for (int cc = 0; cc < 8; ++cc) {
        const int par = cc & 1;
        const char* ApW = Asb[par] + aBase + wm * 4224;   // row wm = dh(-1) row
        const char* BrE = Bsb[par] + bBase;               // read buf, even taps
        const char* BrO = Bsb[par ^ 1] + bBase;           // read buf, odd taps
        char* BwE = (char*)Bsb[par ^ 1];                  // write dst after even tap
        char* BwO = (char*)Bsb[par];                      // write dst after odd tap
        char* Anx = (char*)Asb[par ^ 1];
        const int sbase = cc * 9;
        const bool notlast = (cc < 7);

#pragma unroll
        for (int tap = 0; tap < 9; ++tap) {
            if (tap < 8 || notlast) stageB((tap & 1) ? BwO : BwE, sbase + tap + 1);
            if (tap == 0 && notlast) stageA(Anx, cc + 1);
            SBAR();
            // FIFO-derived counted waits (B=2 loads, A=3 loads)
            if (tap < 2) {
                if (notlast) { asm volatile("s_waitcnt vmcnt(5)" ::: "memory"); }
                else         { asm volatile("s_waitcnt vmcnt(2)" ::: "memory"); }
            } else if (tap == 8) {
                if (notlast) { asm volatile("s_waitcnt vmcnt(2)" ::: "memory"); }
                else         { asm volatile("s_waitcnt vmcnt(0)" ::: "memory"); }
            } else {
                asm volatile("s_waitcnt vmcnt(2)" ::: "memory");
            }
            SBAR();
            asm volatile("s_barrier" ::: "memory");   // stage data ready
            SBAR();

            const int dh = tap / 3 - 1, dw = tap % 3 - 1;
            int hh = h0 + wm + dh;
            if ((unsigned)hh < 64u) {                 // wave-uniform skip
                const char* Ap = ApW;
                const char* Bp = (tap & 1) ? BrO : BrE;
                const int ao = (dh + 1) * 4224 + (dw + 1) * 16;
                bf16x8 a0 = *(const bf16x8*)(Ap + (ao));
                bf16x8 a1 = *(const bf16x8*)(Ap + (ao + 256));
                bf16x8 a2 = *(const bf16x8*)(Ap + (ao + 512));
                bf16x8 a3 = *(const bf16x8*)(Ap + (ao + 768));
#pragma unroll
                for (int nh = 0; nh < 2; ++nh) {
                    bf16x8 b0 = *(const bf16x8*)(Bp + (nh * 1024));
                    bf16x8 b1 = *(const bf16x8*)(Bp + (nh * 1024 + 256));
                    bf16x8 b2 = *(const bf16x8*)(Bp + (nh * 1024 + 512));
                    bf16x8 b3 = *(const bf16x8*)(Bp + (nh * 1024 + 768));
                    __builtin_amdgcn_s_setprio(1);
                    acc[0][nh*4+0] = __builtin_amdgcn_mfma_f32_16x16x32_bf16(a0, b0, acc[0][nh*4+0], 0, 0, 0);
                    acc[1][nh*4+0] = __builtin_amdgcn_mfma_f32_16x16x32_bf16(a1, b0, acc[1][nh*4+0], 0, 0, 0);
                    acc[2][nh*4+0] = __builtin_amdgcn_mfma_f32_16x16x32_bf16(a2, b0, acc[2][nh*4+0], 0, 0, 0);
                    acc[3][nh*4+0] = __builtin_amdgcn_mfma_f32_16x16x32_bf16(a3, b0, acc[3][nh*4+0], 0, 0, 0);
                    acc[0][nh*4+1] = __builtin_amdgcn_mfma_f32_16x16x32_bf16(a0, b1, acc[0][nh*4+1], 0, 0, 0);
                    acc[1][nh*4+1] = __builtin_amdgcn_mfma_f32_16x16x32_bf16(a1, b1, acc[1][nh*4+1], 0, 0, 0);
                    acc[2][nh*4+1] = __builtin_amdgcn_mfma_f32_16x16x32_bf16(a2, b1, acc[2][nh*4+1], 0, 0, 0);
                    acc[3][nh*4+1] = __builtin_amdgcn_mfma_f32_16x16x32_bf16(a3, b1, acc[3][nh*4+1], 0, 0, 0);
                    acc[0][nh*4+2] = __builtin_amdgcn_mfma_f32_16x16x32_bf16(a0, b2, acc[0][nh*4+2], 0, 0, 0);
                    acc[1][nh*4+2] = __builtin_amdgcn_mfma_f32_16x16x32_bf16(a1, b2, acc[1][nh*4+2], 0, 0, 0);
                    acc[2][nh*4+2] = __builtin_amdgcn_mfma_f32_16x16x32_bf16(a2, b2, acc[2][nh*4+2], 0, 0, 0);
                    acc[3][nh*4+2] = __builtin_amdgcn_mfma_f32_16x16x32_bf16(a3, b2, acc[3][nh*4+2], 0, 0, 0);
                    acc[0][nh*4+3] = __builtin_amdgcn_mfma_f32_16x16x32_bf16(a0, b3, acc[0][nh*4+3], 0, 0, 0);
                    acc[1][nh*4+3] = __builtin_amdgcn_mfma_f32_16x16x32_bf16(a1, b3, acc[1][nh*4+3], 0, 0, 0);
                    acc[2][nh*4+3] = __builtin_amdgcn_mfma_f32_16x16x32_bf16(a2, b3, acc[2][nh*4+3], 0, 0, 0);
                    acc[3][nh*4+3] = __builtin_amdgcn_mfma_f32_16x16x32_bf16(a3, b3, acc[3][nh*4+3], 0, 0, 0);
                    __builtin_amdgcn_s_setprio(0);
                }
            }
            SBAR();
            asm volatile("s_barrier" ::: "memory");   // reads done pre-restage
            SBAR();
        }
    }

    // ---------------- epilogue (fast transcendental forms) ----------------
    float cz[8], sh8[8], tz[8];
#pragma unroll
    for (int n = 0; n < 8; ++n) {
        int co = wn * 128 + n * 16 + lrow;
        float zn = znp[co];
        cz[n] = chp[co] / zn;
        sh8[n] = shp[co];
        tz[n] = 2.f * zn;
    }

#pragma unroll
    for (int m = 0; m < 4; ++m) {
#pragma unroll
        for (int r = 0; r < 4; ++r) {
            int wp = wm * 64 + m * 16 + 4 * lk + r;   // block-local px slot
            float s = s_lds[wp], lam = lam_lds[wp];
            float lm1 = lam - 1.f;
            float psum = 0.f;
#pragma unroll
            for (int n = 0; n < 8; ++n) {
                float xz = s * acc[m][n][r];
                float inner = lam * xz * cz[n] - lm1 * sh8[n];
                float as = __logf(inner + sqrtf(inner * inner + 1.f)); // asinh
                float p = __expf(tz[n] * as);
                float w = 0.5f * (p - __builtin_amdgcn_rcpf(p));       // sinh
                acc[m][n][r] = w;
                psum += w * w;
            }
            psum += __shfl_xor(psum, 1);
            psum += __shfl_xor(psum, 2);
            psum += __shfl_xor(psum, 4);
            psum += __shfl_xor(psum, 8);
            if (lrow == 0) red[wp][wn] = psum;
        }
    }
    __syncthreads();

    float dinv[4][4];
#pragma unroll
    for (int m = 0; m < 4; ++m)
#pragma unroll
        for (int r = 0; r < 4; ++r) {
            int wp = wm * 64 + m * 16 + 4 * lk + r;
            float tot = red[wp][0] + red[wp][1];
            dinv[m][r] = __builtin_amdgcn_rcpf(1.f + sqrtf(1.f + tot));
        }

    float* ob = out + (size_t)b * 256 * 4096 + (h0 + wm) * 64;
#pragma unroll
    for (int m = 0; m < 4; ++m) {
#pragma unroll
        for (int n = 0; n < 8; ++n) {
            int co = wn * 128 + n * 16 + lrow;
            f32x4 o;
#pragma unroll
            for (int r = 0; r < 4; ++r) o[r] = acc[m][n][r] * dinv[m][r];
            *(f32x4*)(ob + (size_t)co * 4096 + m * 16 + 4 * lk) = o;
        }
    }
}

// ---------------------------------------------------------------------------
extern "C" void kernel_launch(void* const* d_in, const int* in_sizes, int n_in,
                              void* d_out, int out_size, void* d_ws, size_t ws_size,
                              hipStream_t stream) {
    const float* x = (const float*)d_in[0];   // [16,256,64,64]
    const float* z = (const float*)d_in[1];   // [2304,256]
    const float* r = (const float*)d_in[2];   // [256]
    float* out = (float*)d_out;               // [16,256,64,64]

    char* ws = (char*)d_ws;
    bf16* vt = (bf16*)ws;                         // 33,554,432 B
    float* sq = (float*)(ws + 33554432);
    float* nusq = (float*)(ws + 33816576);
    bf16* zt5 = (bf16*)(ws + 34078720);           // 72*16KB = 1,179,648 B
    float* zn = (float*)(ws + 35258368);
    float* ch = (float*)(ws + 35259392);
    float* sh = (float*)(ws + 35260416);
    if (ws_size < 35261440) return;

    double bni = lgamma(128.0) + lgamma(0.5) - lgamma(128.5);
    double bn = lgamma(1152.0) + lgamma(0.5) - lgamma(1152.5);
    float Rbeta = (float)exp(bn - bni);

    k_prep_zt<<<72, 256, 0, stream>>>(z, zt5);
    k_prep_cols<<<256, 256, 0, stream>>>(z, r, zn, ch, sh);
    k_logmap<<<2048, 256, 0, stream>>>(x, (unsigned int*)vt, sq, Rbeta);
    k_boxsum<<<256, 256, 0, stream>>>(sq, nusq);
    k_hconv<<<256, 512, 0, stream>>>(vt, zt5, nusq, zn, ch, sh, out);
}

// Round 11
// 127.270 us; speedup vs baseline: 1.8584x; 1.1358x over previous
//
#include <hip/hip_runtime.h>
#include <cmath>

typedef __bf16 bf16;
typedef __bf16 bf16x8 __attribute__((ext_vector_type(8)));
typedef float f32x4 __attribute__((ext_vector_type(4)));

#define SBAR() __builtin_amdgcn_sched_barrier(0)

// B=16, C_IN=256, H=W=64, C_OUT=256, 3x3, stride 1, pad 1, CURV=1

__device__ inline void gload16(const void* g, void* l) {
    __builtin_amdgcn_global_load_lds(
        (const __attribute__((address_space(1))) unsigned int*)g,
        (__attribute__((address_space(3))) unsigned int*)l, 16, 0, 0);
}

// ---------------------------------------------------------------------------
// Weight transform: z[k=c*9+tap][co] -> zt5[s=cc*9+tap][gran4][co256][8ch] bf16
__global__ void k_prep_zt(const float* __restrict__ z, bf16* __restrict__ zt5) {
    int s = blockIdx.x;                // 72 = cc*9 + tap, cc in 0..7 (32ch)
    int cc = s / 9, tap = s % 9;
    int co = threadIdx.x;
#pragma unroll
    for (int g = 0; g < 4; ++g) {
        bf16x8 pk;
#pragma unroll
        for (int e = 0; e < 8; ++e) {
            int c = cc * 32 + g * 8 + e;
            pk[e] = (bf16)z[(size_t)(c * 9 + tap) * 256 + co];
        }
        *(bf16x8*)(zt5 + ((size_t)(s * 4 + g) * 256 + co) * 8) = pk;
    }
}

// Column constants
__global__ void k_prep_cols(const float* __restrict__ z, const float* __restrict__ r,
                            float* __restrict__ zn, float* __restrict__ ch,
                            float* __restrict__ sh) {
    __shared__ float red[256];
    int co = blockIdx.x, t = threadIdx.x;
    float s = 0.f;
    for (int i = 0; i < 9; ++i) {
        float v = z[(size_t)(i * 256 + t) * 256 + co];
        s += v * v;
    }
    red[t] = s;
    __syncthreads();
    for (int off = 128; off >= 1; off >>= 1) {
        if (t < off) red[t] += red[t + off];
        __syncthreads();
    }
    if (t == 0) {
        zn[co] = fmaxf(sqrtf(red[0]), 1e-15f);
        float tc = 2.f * r[co];
        ch[co] = coshf(tc);
        sh[co] = sinhf(tc);
    }
}

// ---------------------------------------------------------------------------
__global__ void k_logmap(const float* __restrict__ x, unsigned int* __restrict__ vt_u,
                         float* __restrict__ sq, float Rbeta) {
    __shared__ float tile[256][33];
    __shared__ float red[8][32];
    __shared__ float afac[32];
    int tid = threadIdx.x;
    int blk = blockIdx.x;
    int b = blk >> 7;
    int pix0 = (blk & 127) << 5;

    for (int it = 0; it < 32; ++it) {
        int c = it * 8 + (tid >> 5);
        int p = tid & 31;
        tile[c][p] = x[((size_t)b * 256 + c) * 4096 + pix0 + p];
    }
    __syncthreads();

    {
        int part = tid >> 5, p = tid & 31;
        float s = 0.f;
        for (int i = 0; i < 32; ++i) {
            float v = tile[part * 32 + i][p];
            s += v * v;
        }
        red[part][p] = s;
    }
    __syncthreads();
    if (tid < 32) {
        float n2 = 0.f;
        for (int i = 0; i < 8; ++i) n2 += red[i][tid];
        float n = sqrtf(n2);
        float nc = fmaxf(n, 1e-15f);
        float a = atanhf(fminf(nc, 0.9999999f)) / nc * Rbeta;
        afac[tid] = a;
        sq[(size_t)b * 4096 + pix0 + tid] = a * a * n2;
    }
    __syncthreads();

    for (int it = 0; it < 16; ++it) {
        int idx = it * 256 + tid;
        int p = idx >> 7;
        int cp = idx & 127;
        float a = afac[p];
        float v0 = a * tile[2 * cp][p];
        float v1 = a * tile[2 * cp + 1][p];
        union { bf16 h[2]; unsigned int u; } pk;
        pk.h[0] = (bf16)v0;
        pk.h[1] = (bf16)v1;
        vt_u[((size_t)b * 4096 + pix0 + p) * 128 + cp] = pk.u;
    }
}

__global__ void k_boxsum(const float* __restrict__ sq, float* __restrict__ nusq) {
    int idx = blockIdx.x * 256 + threadIdx.x;
    int b = idx >> 12, hw = idx & 4095, h = hw >> 6, w = hw & 63;
    const float* s = sq + ((size_t)b << 12);
    float acc = 0.f;
    for (int dh = -1; dh <= 1; ++dh) {
        int hh = h + dh;
        if ((unsigned)hh >= 64u) continue;
        for (int dw = -1; dw <= 1; ++dw) {
            int ww = w + dw;
            if ((unsigned)ww >= 64u) continue;
            acc += s[hh * 64 + ww];
        }
    }
    nusq[idx] = acc;
}

// ---------------------------------------------------------------------------
// Fused implicit-GEMM conv + hyperbolic FC epilogue.
// Round-10 lesson: 1 block/CU + 2 waves/SIMD + barrier-phased loop =
// latency-bound (all pipes ~25%, occupancy 20%). This version targets
// 2 blocks/CU so co-resident blocks hide each other's sync latency:
//   Block: 2 rows (128 px) x 256 co, 8 waves (wm row 0..1, wn co-quarter).
//   Wave: 64 px x 64 co (acc[4][4] = 64 regs; waves_per_eu(4,4) -> 128 cap).
//   LDS 67.7 KB: A single-buffered [4r][4g][66-halo] (restage 1x/cc behind a
//   tap8 barrier), B TRIPLE-buffered (read buf tap%3, write (tap+1)%3 --
//   compile-time since 9%3==0; no per-stage trailing barrier needed).
//   Uniform vmcnt(2) (B=2, A=2 loads), vmcnt(0) at last stage. SBAR fences.
__global__ void
__attribute__((amdgpu_flat_work_group_size(512, 512)))
__attribute__((amdgpu_waves_per_eu(4, 4)))
k_hconv(const bf16* __restrict__ vt, const bf16* __restrict__ zt5,
        const float* __restrict__ nusq,
        const float* __restrict__ znp, const float* __restrict__ chp,
        const float* __restrict__ shp, float* __restrict__ out) {
    __shared__ __align__(1024) char Asb[16896];      // 16 units x 1056 B
    __shared__ __align__(1024) char Bsb[3][16448];   // 3 bufs x 4 gran x 4112 B
    __shared__ float s_lds[128], lam_lds[128];
    __shared__ float red[128][4];

    int tid = threadIdx.x;
    int bid = blockIdx.x;
    int bh = ((bid & 7) << 6) | (bid >> 3);   // XCD-bijective: 512 = 8 x 64
    int b = bh >> 5, h0 = (bh & 31) << 1;

    // zero halo slots (0 and 65) of the 16 A units, once
    if (tid < 32) {
        int u = tid >> 1, side = tid & 1;
        *(f32x4*)(Asb + u * 1056 + side * 1040) = (f32x4){0.f, 0.f, 0.f, 0.f};
    }

    if (tid >= 128 && tid < 256) {
        int t = tid - 128;
        int h = h0 + (t >> 6), w = t & 63;
        float q = nusq[((size_t)b << 12) + h * 64 + w];
        float ncl = fmaxf(sqrtf(q), 1e-15f);
        float p = __expf(2.f * ncl);
        float tt = (p - 1.f) / (p + 1.f);        // tanh(ncl)
        s_lds[t] = tt / ncl;                     // expmap scale
        lam_lds[t] = 2.f / (1.f - tt * tt);
    }

    int wave = tid >> 6, lane = tid & 63;
    int wn = wave & 3, wm = wave >> 2;    // wm row 0..1, wn co-quarter 0..3
    int lrow = lane & 15, lk = lane >> 4;

    f32x4 acc[4][4];
#pragma unroll
    for (int m = 0; m < 4; ++m)
#pragma unroll
        for (int n = 0; n < 4; ++n) acc[m][n] = (f32x4){0.f, 0.f, 0.f, 0.f};

    const bf16* vb = vt + (((size_t)b) << 12) * 256;

    // stage A chunk ccn: 16 units (r4 x g4); 2 loads/wave
    auto stageA = [&](int ccn) {
#pragma unroll
        for (int it = 0; it < 2; ++it) {
            int u = wave * 2 + it;
            int r = u >> 2, g = u & 3;
            int hr = h0 - 1 + r;
            hr = hr < 0 ? 0 : (hr > 63 ? 63 : hr);   // clamped rows never read
            const bf16* gp = vb + ((size_t)(hr * 64 + lane)) * 256 + ccn * 32 + g * 8;
            gload16(gp, Asb + u * 1056 + 16);
        }
    };
    // stage B stage snext into buffer dst: linear 16 KB copy; 2 loads/wave
    auto stageB = [&](char* dst, int snext) {
        const char* src = (const char*)zt5 + (size_t)snext * 16384;
#pragma unroll
        for (int it = 0; it < 2; ++it) {
            int u = wave * 2 + it;
            gload16(src + u * 1024 + lane * 16,
                    dst + (u >> 2) * 4112 + (u & 3) * 1024);
        }
    };

    stageB((char*)Bsb[0], 0);
    stageA(0);
    __syncthreads();                      // drains prologue; s_lds visible
    SBAR();

    // per-lane invariant LDS read bases
    const char* ApB = Asb + lk * 1056 + lrow * 16;
    const int bOff = lk * 4112 + wn * 1024 + lrow * 16;

#pragma unroll 1
    for (int cc = 0; cc < 8; ++cc) {
        const int sbase = cc * 9;
        const bool notlast = (cc < 7);

#pragma unroll
        for (int tap = 0; tap < 9; ++tap) {
            const int s = sbase + tap;
            if (s < 71) stageB((char*)Bsb[(tap + 1) % 3], s + 1);
            SBAR();
            if (s < 71) { asm volatile("s_waitcnt vmcnt(2)" ::: "memory"); }
            else        { asm volatile("s_waitcnt vmcnt(0)" ::: "memory"); }
            SBAR();
            asm volatile("s_barrier" ::: "memory");   // stage-s data ready
            SBAR();

            const int dh = tap / 3 - 1, dw = tap % 3 - 1;
            int hh = h0 + wm + dh;
            if ((unsigned)hh < 64u) {                 // wave-uniform skip
                const char* Ap = ApB + (wm + dh + 1) * 4224 + (dw + 1) * 16;
                const char* Bp = (const char*)Bsb[tap % 3] + bOff;
                bf16x8 a0 = *(const bf16x8*)(Ap);
                bf16x8 a1 = *(const bf16x8*)(Ap + 256);
                bf16x8 a2 = *(const bf16x8*)(Ap + 512);
                bf16x8 a3 = *(const bf16x8*)(Ap + 768);
                bf16x8 b0 = *(const bf16x8*)(Bp);
                bf16x8 b1 = *(const bf16x8*)(Bp + 256);
                bf16x8 b2 = *(const bf16x8*)(Bp + 512);
                bf16x8 b3 = *(const bf16x8*)(Bp + 768);
                __builtin_amdgcn_s_setprio(1);
                acc[0][0] = __builtin_amdgcn_mfma_f32_16x16x32_bf16(a0, b0, acc[0][0], 0, 0, 0);
                acc[1][0] = __builtin_amdgcn_mfma_f32_16x16x32_bf16(a1, b0, acc[1][0], 0, 0, 0);
                acc[2][0] = __builtin_amdgcn_mfma_f32_16x16x32_bf16(a2, b0, acc[2][0], 0, 0, 0);
                acc[3][0] = __builtin_amdgcn_mfma_f32_16x16x32_bf16(a3, b0, acc[3][0], 0, 0, 0);
                acc[0][1] = __builtin_amdgcn_mfma_f32_16x16x32_bf16(a0, b1, acc[0][1], 0, 0, 0);
                acc[1][1] = __builtin_amdgcn_mfma_f32_16x16x32_bf16(a1, b1, acc[1][1], 0, 0, 0);
                acc[2][1] = __builtin_amdgcn_mfma_f32_16x16x32_bf16(a2, b1, acc[2][1], 0, 0, 0);
                acc[3][1] = __builtin_amdgcn_mfma_f32_16x16x32_bf16(a3, b1, acc[3][1], 0, 0, 0);
                acc[0][2] = __builtin_amdgcn_mfma_f32_16x16x32_bf16(a0, b2, acc[0][2], 0, 0, 0);
                acc[1][2] = __builtin_amdgcn_mfma_f32_16x16x32_bf16(a1, b2, acc[1][2], 0, 0, 0);
                acc[2][2] = __builtin_amdgcn_mfma_f32_16x16x32_bf16(a2, b2, acc[2][2], 0, 0, 0);
                acc[3][2] = __builtin_amdgcn_mfma_f32_16x16x32_bf16(a3, b2, acc[3][2], 0, 0, 0);
                acc[0][3] = __builtin_amdgcn_mfma_f32_16x16x32_bf16(a0, b3, acc[0][3], 0, 0, 0);
                acc[1][3] = __builtin_amdgcn_mfma_f32_16x16x32_bf16(a1, b3, acc[1][3], 0, 0, 0);
                acc[2][3] = __builtin_amdgcn_mfma_f32_16x16x32_bf16(a2, b3, acc[2][3], 0, 0, 0);
                acc[3][3] = __builtin_amdgcn_mfma_f32_16x16x32_bf16(a3, b3, acc[3][3], 0, 0, 0);
                __builtin_amdgcn_s_setprio(0);
            }
            SBAR();
            if (tap == 8) {
                // cc tail: all A[cc] reads done -> safe to restage A in place
                asm volatile("s_barrier" ::: "memory");
                SBAR();
                if (notlast) stageA(cc + 1);
                SBAR();
            }
        }
    }

    // ---------------- epilogue (fast transcendental forms) ----------------
    float cz[4], sh4[4], tz[4];
#pragma unroll
    for (int n = 0; n < 4; ++n) {
        int co = wn * 64 + n * 16 + lrow;
        float zn = znp[co];
        cz[n] = chp[co] / zn;
        sh4[n] = shp[co];
        tz[n] = 2.f * zn;
    }

#pragma unroll
    for (int m = 0; m < 4; ++m) {
#pragma unroll
        for (int r = 0; r < 4; ++r) {
            int wp = wm * 64 + m * 16 + 4 * lk + r;   // block-local px slot
            float s = s_lds[wp], lam = lam_lds[wp];
            float lm1 = lam - 1.f;
            float psum = 0.f;
#pragma unroll
            for (int n = 0; n < 4; ++n) {
                float xz = s * acc[m][n][r];
                float inner = lam * xz * cz[n] - lm1 * sh4[n];
                float as = __logf(inner + sqrtf(inner * inner + 1.f)); // asinh
                float p = __expf(tz[n] * as);
                float w = 0.5f * (p - __builtin_amdgcn_rcpf(p));       // sinh
                acc[m][n][r] = w;
                psum += w * w;
            }
            psum += __shfl_xor(psum, 1);
            psum += __shfl_xor(psum, 2);
            psum += __shfl_xor(psum, 4);
            psum += __shfl_xor(psum, 8);
            if (lrow == 0) red[wp][wn] = psum;
        }
    }
    __syncthreads();

    float dinv[4][4];
#pragma unroll
    for (int m = 0; m < 4; ++m)
#pragma unroll
        for (int r = 0; r < 4; ++r) {
            int wp = wm * 64 + m * 16 + 4 * lk + r;
            float tot = (red[wp][0] + red[wp][1]) + (red[wp][2] + red[wp][3]);
            dinv[m][r] = __builtin_amdgcn_rcpf(1.f + sqrtf(1.f + tot));
        }

    float* ob = out + (size_t)b * 256 * 4096 + (h0 + wm) * 64;
#pragma unroll
    for (int m = 0; m < 4; ++m) {
#pragma unroll
        for (int n = 0; n < 4; ++n) {
            int co = wn * 64 + n * 16 + lrow;
            f32x4 o;
#pragma unroll
            for (int r = 0; r < 4; ++r) o[r] = acc[m][n][r] * dinv[m][r];
            *(f32x4*)(ob + (size_t)co * 4096 + m * 16 + 4 * lk) = o;
        }
    }
}

// ---------------------------------------------------------------------------
extern "C" void kernel_launch(void* const* d_in, const int* in_sizes, int n_in,
                              void* d_out, int out_size, void* d_ws, size_t ws_size,
                              hipStream_t stream) {
    const float* x = (const float*)d_in[0];   // [16,256,64,64]
    const float* z = (const float*)d_in[1];   // [2304,256]
    const float* r = (const float*)d_in[2];   // [256]
    float* out = (float*)d_out;               // [16,256,64,64]

    char* ws = (char*)d_ws;
    bf16* vt = (bf16*)ws;                         // 33,554,432 B
    float* sq = (float*)(ws + 33554432);
    float* nusq = (float*)(ws + 33816576);
    bf16* zt5 = (bf16*)(ws + 34078720);           // 72*16KB = 1,179,648 B
    float* zn = (float*)(ws + 35258368);
    float* ch = (float*)(ws + 35259392);
    float* sh = (float*)(ws + 35260416);
    if (ws_size < 35261440) return;

    double bni = lgamma(128.0) + lgamma(0.5) - lgamma(128.5);
    double bn = lgamma(1152.0) + lgamma(0.5) - lgamma(1152.5);
    float Rbeta = (float)exp(bn - bni);

    k_prep_zt<<<72, 256, 0, stream>>>(z, zt5);
    k_prep_cols<<<256, 256, 0, stream>>>(z, r, zn, ch, sh);
    k_logmap<<<2048, 256, 0, stream>>>(x, (unsigned int*)vt, sq, Rbeta);
    k_boxsum<<<256, 256, 0, stream>>>(sq, nusq);
    k_hconv<<<512, 512, 0, stream>>>(vt, zt5, nusq, zn, ch, sh, out);
}